// Round 2
// baseline (626.132 us; speedup 1.0000x reference)
//
#include <hip/hip_runtime.h>

// KoopmanOperator via split-bf16 MFMA, v2: 2 waves/SIMD occupancy + VALU diet.
// Block = 8 batch rows (rows 8-15 of the M=16 MFMA are bounded garbage), 4 waves.
// Wave w owns output-dim tile [16w,16w+16). Weights resident in VGPRs as B-frags,
// W = Whi + Wlo (bf16 split). y/h exchanged via XOR-swizzled bf16 LDS planes.
// Rotation trig via small-angle polynomials: |dt*p| <= ~0.08 GUARANTEED because
// p = W2·tanh(..)+b2 is bounded by row L1 norms (tanh in [-1,1]) — poly errors
// (exp deg4 ~3e-8, cos deg6 ~4e-13, sin deg7 ~1e-11) beat the hw transcendentals.

#define T_STEPS 256
#define DD 64
#define DT 0.01f
#define ROWS 8   // batch rows per block

typedef __attribute__((ext_vector_type(8))) short short8;  // 8 bf16 = 4 VGPR
typedef __attribute__((ext_vector_type(4))) float f32x4;   // C/D frag

#define MFMA_BF16(a, b, c) __builtin_amdgcn_mfma_f32_16x16x32_bf16((a), (b), (c), 0, 0, 0)

static __device__ __forceinline__ short bf16_rne(float f) {
    unsigned u = __float_as_uint(f);
    u += 0x7FFFu + ((u >> 16) & 1u);       // round-to-nearest-even
    return (short)(u >> 16);
}
static __device__ __forceinline__ short bf16_trunc(float f) {
    return (short)(__float_as_uint(f) >> 16);   // 1 op; lo-plane compensates resid
}
static __device__ __forceinline__ float bf16_f32(short s) {
    return __uint_as_float(((unsigned)(unsigned short)s) << 16);
}

__global__ __launch_bounds__(256, 2) void koopman_mfma(
    const float* __restrict__ x,
    const float* __restrict__ W1, const float* __restrict__ b1,
    const float* __restrict__ W2, const float* __restrict__ b2,
    float* __restrict__ out)
{
    // bf16 planes: [16 rows][64 dims], row stride 128 B (rows 8-15 = garbage lanes)
    __shared__ short y_hi[16 * DD], y_lo[16 * DD];
    __shared__ short h_hi[16 * DD], h_lo[16 * DD];

    const int tid   = threadIdx.x;
    const int w     = tid >> 6;        // wave 0..3 = output-dim tile
    const int lane  = tid & 63;
    const int m     = lane & 15;       // A-frag row (batch) / C-frag col (dim)
    const int g     = lane >> 4;       // k-group; C-frag rows g*4..g*4+3
    const int row0  = g << 2;
    const int b0    = blockIdx.x * ROWS;
    const int dglob = (w << 4) + m;    // global dim this lane owns in C/D
    const bool even   = ((lane & 1) == 0);
    const bool gvalid = (g < 2);       // C/D rows 0..7 are real batch rows

    // ---- Weight B-fragments (hi/lo split), resident in VGPRs ----
    // B[k][n] = W[n][k]; lane: n = m (dim within tile), k = kt*32 + g*8 + e.
    short8 w1h[2], w1l[2], w2h[2], w2l[2];
    #pragma unroll
    for (int kt = 0; kt < 2; ++kt) {
        const float* p1 = W1 + (size_t)dglob * DD + (kt << 5) + (g << 3);
        const float* p2 = W2 + (size_t)dglob * DD + (kt << 5) + (g << 3);
        #pragma unroll
        for (int e = 0; e < 8; ++e) {
            float v1 = p1[e];
            short h1 = bf16_rne(v1);
            w1h[kt][e] = h1;
            w1l[kt][e] = bf16_rne(v1 - bf16_f32(h1));
            float v2 = p2[e];
            short h2 = bf16_rne(v2);
            w2h[kt][e] = h2;
            w2l[kt][e] = bf16_rne(v2 - bf16_f32(h2));
        }
    }
    const float b1r = b1[dglob];
    const float b2r = b2[dglob];

    // ---- Loop-invariant LDS byte offsets (XOR swizzle: byte ^= (row&7)<<4) ----
    int wbyte[4];
    #pragma unroll
    for (int r = 0; r < 4; ++r) {
        int row  = row0 + r;
        wbyte[r] = ((row << 7) + (dglob << 1)) ^ ((row & 7) << 4);
    }
    int rbyte[2];
    #pragma unroll
    for (int kt = 0; kt < 2; ++kt) {
        int d0    = (kt << 5) + (g << 3);
        rbyte[kt] = ((m << 7) + (d0 << 1)) ^ ((m & 7) << 4);
    }

    // ---- Initial state: y0 = x[:,0,:]; garbage rows start at 0 (stay bounded) ----
    float yv[4];
    unsigned obase[4];
    #pragma unroll
    for (int r = 0; r < 4; ++r) {
        int row  = row0 + r;
        yv[r]    = gvalid ? x[((size_t)(b0 + row) * T_STEPS) * DD + dglob] : 0.0f;
        obase[r] = gvalid ? ((unsigned)(b0 + row) * T_STEPS * DD + dglob) : 0u;
    }
    #pragma unroll
    for (int r = 0; r < 4; ++r) {
        short hs = bf16_trunc(yv[r]);
        *(short*)((char*)y_hi + wbyte[r]) = hs;
        *(short*)((char*)y_lo + wbyte[r]) = bf16_rne(yv[r] - bf16_f32(hs));
    }
    __syncthreads();

    for (int t = 0; t < T_STEPS; ++t) {
        // ---- matvec1: a = Y W1^T (3-product split-bf16, f32 accum) ----
        short8 ah0 = *(const short8*)((const char*)y_hi + rbyte[0]);
        short8 al0 = *(const short8*)((const char*)y_lo + rbyte[0]);
        short8 ah1 = *(const short8*)((const char*)y_hi + rbyte[1]);
        short8 al1 = *(const short8*)((const char*)y_lo + rbyte[1]);
        f32x4 acc0 = {0.f, 0.f, 0.f, 0.f};
        f32x4 acc1 = {0.f, 0.f, 0.f, 0.f};
        acc0 = MFMA_BF16(ah0, w1h[0], acc0);
        acc1 = MFMA_BF16(ah1, w1h[1], acc1);
        acc0 = MFMA_BF16(al0, w1h[0], acc0);
        acc1 = MFMA_BF16(al1, w1h[1], acc1);
        acc0 = MFMA_BF16(ah0, w1l[0], acc0);
        acc1 = MFMA_BF16(ah1, w1l[1], acc1);

        // ---- h = tanh(a + b1); stage bf16 hi/lo ----
        #pragma unroll
        for (int r = 0; r < 4; ++r) {
            float a  = acc0[r] + acc1[r] + b1r;
            float ex = __expf(2.0f * a);                  // inf-safe: th -> +/-1
            float th = 1.0f - __fdividef(2.0f, ex + 1.0f);
            short hs = bf16_trunc(th);
            *(short*)((char*)h_hi + wbyte[r]) = hs;
            *(short*)((char*)h_lo + wbyte[r]) = bf16_rne(th - bf16_f32(hs));
        }
        __syncthreads();

        // ---- matvec2: p = H W2^T ----
        ah0 = *(const short8*)((const char*)h_hi + rbyte[0]);
        al0 = *(const short8*)((const char*)h_lo + rbyte[0]);
        ah1 = *(const short8*)((const char*)h_hi + rbyte[1]);
        al1 = *(const short8*)((const char*)h_lo + rbyte[1]);
        f32x4 pc0 = {0.f, 0.f, 0.f, 0.f};
        f32x4 pc1 = {0.f, 0.f, 0.f, 0.f};
        pc0 = MFMA_BF16(ah0, w2h[0], pc0);
        pc1 = MFMA_BF16(ah1, w2h[1], pc1);
        pc0 = MFMA_BF16(al0, w2h[0], pc0);
        pc1 = MFMA_BF16(al1, w2h[1], pc1);
        pc0 = MFMA_BF16(ah0, w2l[0], pc0);
        pc1 = MFMA_BF16(ah1, w2l[1], pc1);

        // ---- rotation update (exact f32, poly trig); pairs = adjacent lanes ----
        // even lane(2i): n = e*(c*y_s - s*y_o); odd(2i+1): n = e*(s*y_o - c*y_s)
        // => u = s*y_o - c*y_s;  n = (even ? -e : e) * u   (3 selects total)
        #pragma unroll
        for (int r = 0; r < 4; ++r) {
            float p   = pc0[r] + pc1[r] + b2r;
            float p_o = __shfl_xor(p, 1, 64);
            float y_o = __shfl_xor(yv[r], 1, 64);
            float xm  = DT * (even ? p   : p_o);   // dt*mu
            float xo  = DT * (even ? p_o : p);     // dt*omega, |x| <= ~0.08
            float e   = fmaf(xm, fmaf(xm, fmaf(xm, fmaf(xm, 1.f/24.f, 1.f/6.f), 0.5f), 1.f), 1.f);
            float z   = xo * xo;
            float c   = fmaf(z, fmaf(z, fmaf(z, -1.f/720.f, 1.f/24.f), -0.5f), 1.f);
            float s   = xo * fmaf(z, fmaf(z, fmaf(z, -1.f/5040.f, 1.f/120.f), -1.f/6.f), 1.f);
            float u   = fmaf(s, y_o, -(c * yv[r]));
            float es  = even ? -e : e;
            float n   = es * u;
            yv[r] = n;
            if (gvalid) out[obase[r] + (unsigned)(t << 6)] = n;
            short hs = bf16_trunc(n);
            *(short*)((char*)y_hi + wbyte[r]) = hs;
            *(short*)((char*)y_lo + wbyte[r]) = bf16_rne(n - bf16_f32(hs));
        }
        __syncthreads();   // y planes ready for next step
    }
}

extern "C" void kernel_launch(void* const* d_in, const int* in_sizes, int n_in,
                              void* d_out, int out_size, void* d_ws, size_t ws_size,
                              hipStream_t stream) {
    const float* x  = (const float*)d_in[0];
    const float* W1 = (const float*)d_in[1];
    const float* b1 = (const float*)d_in[2];
    const float* W2 = (const float*)d_in[3];
    const float* b2 = (const float*)d_in[4];
    float* out = (float*)d_out;

    dim3 grid(4096 / ROWS);   // 512 blocks = 2 per CU -> 2 waves/SIMD
    dim3 block(256);          // 4 waves: one 16-dim output tile each
    koopman_mfma<<<grid, block, 0, stream>>>(x, W1, b1, W2, b2, out);
}